// Round 4
// baseline (919.363 us; speedup 1.0000x reference)
//
#include <hip/hip_runtime.h>

// LightGCN 3-layer propagation: two-pass binned CSR build + octet-gather SpMM.
// out layout: [4, N_NODES, DIM] f32.
//   layer 0 = embeddings (copy)
//   layer l = SpMM(layer l-1):  y[d] = sum_{e: dst(e)=d} w[e] * x[src(e)]
//
// R3 counters: one-pass scatter wrote 77.5 MB for a 9.6 MB payload (random 8B
// stores -> 64B-line write-allocate, 8x amplification), 63 us. spmm <63 us but
// still latency-bound with 4 gather chains/wave.
// R4: (1) coarse-bin edges into 782 buckets of 128 nodes (sequential per-bucket
// streams), then one-block-per-bucket fine scatter confined to ~12 KB windows
// (L2 coalesces writebacks). tmp buffer aliases out-layer1 (overwritten later).
// (2) octet spmm: 8 edges in flight per wave, lane = 8 dims (2x float4).

#define N_NODES 100000
#define DIM 64
#define SCAN_CHUNK 1024
#define BSHIFT 7                     // 128 nodes per bucket
#define NB ((N_NODES + 127) / 128)   // 782 buckets

// ---------------- fused histogram: per-dst degree + per-bucket count --------

__global__ void build_hist_kernel(const int* __restrict__ edst,
                                  int* __restrict__ deg,
                                  int* __restrict__ histB, int E) {
    int e = blockIdx.x * blockDim.x + threadIdx.x;
    if (e >= E) return;
    int d = edst[e];
    atomicAdd(&deg[d], 1);
    atomicAdd(&histB[d >> BSHIFT], 1);
}

// ---------------- bucket scan (single block, NB <= 1024) --------------------

__global__ void scanB_kernel(const int* __restrict__ histB,
                             int* __restrict__ offB, int* __restrict__ curB) {
    __shared__ int s[1024];
    int tid = threadIdx.x;
    int v = (tid < NB) ? histB[tid] : 0;
    s[tid] = v;
    __syncthreads();
    for (int d = 1; d < 1024; d <<= 1) {
        int t = (tid >= d) ? s[tid - d] : 0;
        __syncthreads();
        s[tid] += t;
        __syncthreads();
    }
    if (tid < NB) {
        int excl = s[tid] - v;
        offB[tid] = excl;
        curB[tid] = excl;
    }
}

// ---------------- per-dst offset scan (3 stages) ----------------------------

__global__ void scan1_kernel(const int* __restrict__ deg, int* __restrict__ off,
                             int* __restrict__ bsum, int n) {
    __shared__ int sdata[256];
    int tid = threadIdx.x;
    int base = blockIdx.x * SCAN_CHUNK + tid * 4;
    int v[4];
    #pragma unroll
    for (int i = 0; i < 4; ++i) v[i] = (base + i < n) ? deg[base + i] : 0;
    int tsum = v[0] + v[1] + v[2] + v[3];
    sdata[tid] = tsum;
    __syncthreads();
    for (int d = 1; d < 256; d <<= 1) {
        int t = (tid >= d) ? sdata[tid - d] : 0;
        __syncthreads();
        sdata[tid] += t;
        __syncthreads();
    }
    int excl = sdata[tid] - tsum;
    if (tid == 255) bsum[blockIdx.x] = sdata[255];
    int run = excl;
    #pragma unroll
    for (int i = 0; i < 4; ++i) {
        if (base + i < n) off[base + i] = run;
        run += v[i];
    }
}

__global__ void scan2_kernel(int* __restrict__ bsum, int nb) {
    __shared__ int s[128];
    int tid = threadIdx.x;
    int v = (tid < nb) ? bsum[tid] : 0;
    s[tid] = v;
    __syncthreads();
    for (int d = 1; d < 128; d <<= 1) {
        int t = (tid >= d) ? s[tid - d] : 0;
        __syncthreads();
        s[tid] += t;
        __syncthreads();
    }
    if (tid < nb) bsum[tid] = s[tid] - v;
}

__global__ void scan3_kernel(int* __restrict__ off, const int* __restrict__ bsum, int n) {
    int i = blockIdx.x * blockDim.x + threadIdx.x;
    if (i < n) off[i] += bsum[i / SCAN_CHUNK];
}

// ---------------- pass A: coarse bin (sequential per-bucket streams) --------
// tmp entry: { (src << 7) | (dst & 127), weight_bits }  (src < 2^17 fits)

__global__ void binA_kernel(const int* __restrict__ esrc, const int* __restrict__ edst,
                            const float* __restrict__ ew, int* __restrict__ curB,
                            int2* __restrict__ tmp, int E) {
    int e = blockIdx.x * blockDim.x + threadIdx.x;
    if (e >= E) return;
    int d = edst[e];
    int b = d >> BSHIFT;
    int p = atomicAdd(&curB[b], 1);
    int2 t;
    t.x = (esrc[e] << BSHIFT) | (d & 127);
    t.y = __float_as_int(ew[e]);
    tmp[p] = t;
}

// ---------------- pass B: fine scatter, one block per bucket ----------------
// All writes land in this bucket's ~12 KB window of `pairs` -> L2-coalesced.

__global__ void binB_kernel(const int2* __restrict__ tmp,
                            const int* __restrict__ offB, const int* __restrict__ histB,
                            const int* __restrict__ off, int* __restrict__ cur,
                            int2* __restrict__ pairs) {
    int b = blockIdx.x;
    int start = offB[b];
    int cnt = histB[b];
    for (int i = threadIdx.x; i < cnt; i += blockDim.x) {
        int2 t = tmp[start + i];
        int dst = (b << BSHIFT) | (t.x & 127);
        int src = t.x >> BSHIFT;
        int p = off[dst] + atomicAdd(&cur[dst], 1);
        int2 pr; pr.x = src; pr.y = t.y;
        pairs[p] = pr;
    }
}

// ---------------- SpMM: one wave per node, 8 edges in flight ----------------
// Octet o (lanes 8o..8o+7) processes edges k = o, o+8, ... Lane covers 8 dims
// (two float4s). Cross-octet sum via shfl_xor(8,16,32); octet 0 stores.

__global__ void spmm_octet_kernel(const float* __restrict__ x,
                                  const int2* __restrict__ pairs,
                                  const int* __restrict__ off,
                                  const int* __restrict__ deg,
                                  float* __restrict__ y) {
    int gtid = blockIdx.x * blockDim.x + threadIdx.x;
    int node = gtid >> 6;
    int lane = threadIdx.x & 63;
    int oct = lane >> 3;   // which edge of the group of 8
    int ol  = lane & 7;    // which 8-dim slice of the row
    if (node >= N_NODES) return;
    int s0 = off[node];
    int n  = deg[node];
    float4 a0 = make_float4(0.f, 0.f, 0.f, 0.f);
    float4 a1 = make_float4(0.f, 0.f, 0.f, 0.f);
    for (int k = oct; k < n; k += 8) {
        int2 pr = pairs[s0 + k];                  // broadcast within octet
        float w = __int_as_float(pr.y);
        const float4* row = (const float4*)(x + (size_t)pr.x * DIM);
        float4 v0 = row[2 * ol];
        float4 v1 = row[2 * ol + 1];              // independent 16B loads
        a0.x += w * v0.x; a0.y += w * v0.y; a0.z += w * v0.z; a0.w += w * v0.w;
        a1.x += w * v1.x; a1.y += w * v1.y; a1.z += w * v1.z; a1.w += w * v1.w;
    }
    #pragma unroll
    for (int d = 8; d < 64; d <<= 1) {
        a0.x += __shfl_xor(a0.x, d); a0.y += __shfl_xor(a0.y, d);
        a0.z += __shfl_xor(a0.z, d); a0.w += __shfl_xor(a0.w, d);
        a1.x += __shfl_xor(a1.x, d); a1.y += __shfl_xor(a1.y, d);
        a1.z += __shfl_xor(a1.z, d); a1.w += __shfl_xor(a1.w, d);
    }
    if (oct == 0) {
        float4* yrow = (float4*)(y + (size_t)node * DIM);
        yrow[2 * ol]     = a0;
        yrow[2 * ol + 1] = a1;
    }
}

// ---------------- fallback (atomic path, if ws too small) -------------------

__global__ void spmm_atomic_kernel(const float* __restrict__ x, const float* __restrict__ ew,
                                   const int* __restrict__ esrc, const int* __restrict__ edst,
                                   float* __restrict__ y, int n_edges) {
    long long tid = (long long)blockIdx.x * blockDim.x + threadIdx.x;
    int e = (int)(tid >> 6);
    int d = (int)(tid & 63);
    if (e >= n_edges) return;
    int s = esrc[e]; int t = edst[e]; float w = ew[e];
    atomicAdd(&y[(long long)t * DIM + d], w * x[(long long)s * DIM + d]);
}

extern "C" void kernel_launch(void* const* d_in, const int* in_sizes, int n_in,
                              void* d_out, int out_size, void* d_ws, size_t ws_size,
                              hipStream_t stream) {
    const float* emb  = (const float*)d_in[0];
    const float* ew   = (const float*)d_in[1];
    const int*   esrc = (const int*)d_in[2];
    const int*   edst = (const int*)d_in[3];
    float* out = (float*)d_out;

    const int E = in_sizes[1];
    const size_t layer_elems = (size_t)N_NODES * DIM;

    // ws layout: pairs | deg | cur | histB | off | bsum | offB | curB
    size_t need = (size_t)E * 8 +
                  ((size_t)3 * N_NODES + NB * 3 + 128 + 16) * 4;

    hipMemcpyAsync(out, emb, layer_elems * sizeof(float), hipMemcpyDeviceToDevice, stream);

    if (ws_size >= need) {
        char* w = (char*)d_ws;
        int2* pairs = (int2*)w;
        int* deg   = (int*)(w + (size_t)E * 8);
        int* cur   = deg + N_NODES;
        int* histB = cur + N_NODES;          // contiguous with deg/cur for one memset
        int* off   = histB + NB;
        int* bsum  = off + N_NODES;
        int* offB  = bsum + 128;
        int* curB  = offB + NB;
        // tmp (coarse-binned edges) aliases out layer 1 — overwritten by spmm later.
        int2* tmp = (int2*)(out + layer_elems);

        // Zero deg + cur + histB in one shot (ws is poisoned 0xAA each launch).
        hipMemsetAsync(deg, 0, ((size_t)2 * N_NODES + NB) * 4, stream);

        const int eb = (E + 255) / 256;
        build_hist_kernel<<<eb, 256, 0, stream>>>(edst, deg, histB, E);

        scanB_kernel<<<1, 1024, 0, stream>>>(histB, offB, curB);

        const int nscan = (N_NODES + SCAN_CHUNK - 1) / SCAN_CHUNK;   // 98
        scan1_kernel<<<nscan, 256, 0, stream>>>(deg, off, bsum, N_NODES);
        scan2_kernel<<<1, 128, 0, stream>>>(bsum, nscan);
        scan3_kernel<<<(N_NODES + 255) / 256, 256, 0, stream>>>(off, bsum, N_NODES);

        binA_kernel<<<eb, 256, 0, stream>>>(esrc, edst, ew, curB, tmp, E);
        binB_kernel<<<NB, 256, 0, stream>>>(tmp, offB, histB, off, cur, pairs);

        const int nb = (N_NODES + 3) / 4;   // 4 waves (nodes) per 256-thread block
        for (int l = 1; l <= 3; ++l) {
            spmm_octet_kernel<<<nb, 256, 0, stream>>>(
                out + (size_t)(l - 1) * layer_elems, pairs, off, deg,
                out + (size_t)l * layer_elems);
        }
    } else {
        hipMemsetAsync(out + layer_elems, 0, 3 * layer_elems * sizeof(float), stream);
        const long long total_threads = (long long)E * 64;
        const int blocks = (int)((total_threads + 255) / 256);
        for (int l = 1; l <= 3; ++l) {
            spmm_atomic_kernel<<<blocks, 256, 0, stream>>>(
                out + (size_t)(l - 1) * layer_elems, ew, esrc, edst,
                out + (size_t)l * layer_elems, E);
        }
    }
}